// Round 5
// baseline (973.091 us; speedup 1.0000x reference)
//
#include <hip/hip_runtime.h>

// PathGCN fused layer — fp32, correctness-first scalar version.
// out[n,j] = relu( sum_d res[n,d] * fcw[j,d] )
// res[n,d] = (1/8) * sum_l pw[l,d] * ( sum_p feats[ paths[p,n,l], d ] )
//
// All floating tensors are float32 (per the reference). One block per node,
// 128 threads (= HIDDEN). Phase 1: thread d computes res[n,d]; feats rows
// are read coalesced across the block (128 x 4 B = 512 B per row). Phase 2:
// thread j computes out[n,j] from the LDS res vector (broadcast reads) and
// fcw row j (64 KB total, cache resident).

#define N_NODES 100000
#define HIDDEN  128
#define NPATH   8
#define PLEN    8

__global__ void PathGCNLayer_61306363183203_kernel(
    const float* feats,   // (N, 128) f32
    const int*   paths,   // (8, N, 8) int32
    const float* pw,      // (8, 128) f32  (path_weight[0])
    const float* fcw,     // (128, 128) f32, row j = output dim
    float*       out)     // (N, 128) f32
{
    __shared__ int   sidx[NPATH * PLEN];   // [p][l] for this node
    __shared__ float sres[HIDDEN];

    const int n = blockIdx.x;
    const int d = threadIdx.x;             // 0..127

    if (d < NPATH * PLEN) {
        const int p = d / PLEN;
        const int l = d - p * PLEN;
        sidx[d] = paths[(size_t)p * (size_t)N_NODES * PLEN + (size_t)n * PLEN + l];
    }
    __syncthreads();

    // phase 1: res[n, d]
    float acc = 0.0f;
    for (int l = 0; l < PLEN; ++l) {
        float s = 0.0f;
        for (int p = 0; p < NPATH; ++p) {
            const int idx = sidx[p * PLEN + l];
            s = s + feats[(size_t)idx * HIDDEN + d];
        }
        acc = acc + s * pw[l * HIDDEN + d];
    }
    sres[d] = acc * 0.125f;
    __syncthreads();

    // phase 2: out[n, j] with j = d
    float o = 0.0f;
    for (int k = 0; k < HIDDEN; ++k) {
        o = o + sres[k] * fcw[d * HIDDEN + k];
    }
    if (o < 0.0f) o = 0.0f;
    out[(size_t)n * HIDDEN + d] = o;
}

extern "C" void kernel_launch(void* const* d_in, const int* in_sizes, int n_in,
                              void* d_out, int out_size, void* d_ws, size_t ws_size,
                              hipStream_t stream) {
    const float* feats = (const float*)d_in[0];   // (N,128) f32
    const int*   paths = (const int*)d_in[1];     // (8,N,8) int32
    // d_in[2] = init_feats — unused by the reference
    const float* pw    = (const float*)d_in[3];   // (1,8,128) f32
    const float* fcw   = (const float*)d_in[4];   // (128,128) f32
    float* out = (float*)d_out;
    (void)in_sizes; (void)n_in; (void)out_size; (void)d_ws; (void)ws_size;

    PathGCNLayer_61306363183203_kernel<<<N_NODES, HIDDEN, 0, stream>>>(
        feats, paths, pw, fcw, out);
}

// Round 6
// 535.027 us; speedup vs baseline: 1.8188x; 1.8188x over previous
//
#include <hip/hip_runtime.h>

// PathGCN fused layer — fp32.
// out[n,j] = relu( sum_k res[n,k] * fcw[j,k] )
// res[n,k] = (1/8) * sum_l pw[l,k] * ( sum_p feats[ paths[p,n,l], k ] )
//
// 8 nodes per 256-thread block; thread (node, c) owns float4 column c.
// Phase 1: vectorized gather (16 B/lane, 512 B per feats row, 2 rows per
// wave access). Phase 2: fcw staged in LDS k-tiles (padded stride 33 ->
// conflict-free), j = c + 32*jj so fcw tile loads are coalesced and LDS
// reads are bank-spread; kills the 64-distinct-line-per-instr divergence
// that dominated the previous version.

#define N_NODES 100000
#define HIDDEN  128
#define NPATH   8
#define PLEN    8
#define NPB     8      // nodes per block (256 threads = 8 nodes x 32 lanes)
#define KT      32     // k-tile width for fcw staging

__global__ void PathGCNLayer_61306363183203_kernel(
    const float4* feats4,   // (N, 32) as float4 rows
    const int*    paths,    // (8, N, 8) int32
    const float4* pw4,      // (8, 32) as float4 rows
    const float4* fcw4,     // (128, 32) as float4 rows
    float*        out)      // (N, 128) f32
{
    __shared__ int    sidx[NPATH * NPB * PLEN];  // [p][node][l], p-major
    __shared__ float4 sres4[NPB][33];            // res tile, pad breaks stride
    __shared__ float  fcwt[HIDDEN][KT + 1];      // fcw k-tile, pad -> (c+k)%32

    const int tid  = threadIdx.x;
    const int n0   = blockIdx.x * NPB;
    const int node = tid >> 5;      // 0..7
    const int c    = tid & 31;      // float4 column within row

    // ---- stage 512 path indices (for each p: 64 consecutive ints) ----
    {
        const int p = tid >> 5;     // 0..7
        const int i = tid & 31;
        const size_t base = (size_t)p * (N_NODES * PLEN) + (size_t)n0 * PLEN;
        sidx[p * 64 + i]      = paths[base + i];
        sidx[p * 64 + i + 32] = paths[base + i + 32];
    }
    __syncthreads();

    // ---- phase 1: res[node][4c..4c+3] ----
    float ax = 0.0f, ay = 0.0f, az = 0.0f, aw = 0.0f;
    for (int l = 0; l < PLEN; ++l) {
        float sx = 0.0f, sy = 0.0f, sz = 0.0f, sw = 0.0f;
        for (int p = 0; p < NPATH; ++p) {
            const int idx = sidx[p * 64 + node * PLEN + l];
            const float4 v = feats4[(size_t)idx * 32 + c];
            sx += v.x; sy += v.y; sz += v.z; sw += v.w;
        }
        const float4 w = pw4[l * 32 + c];
        ax = fmaf(sx, w.x, ax);
        ay = fmaf(sy, w.y, ay);
        az = fmaf(sz, w.z, az);
        aw = fmaf(sw, w.w, aw);
    }
    {
        float4 r;
        r.x = ax * 0.125f; r.y = ay * 0.125f;
        r.z = az * 0.125f; r.w = aw * 0.125f;
        sres4[node][c] = r;
    }

    // ---- phase 2: out[node][j], j = c + 32*jj, over 4 fcw k-tiles ----
    float o0 = 0.0f, o1 = 0.0f, o2 = 0.0f, o3 = 0.0f;

    for (int kt = 0; kt < HIDDEN / KT; ++kt) {
        __syncthreads();   // protect fcwt reuse (and sres on first iter)
        // stage fcw[:, kt*32 .. kt*32+31] -> fcwt[j][k'] (coalesced global)
        {
            const int j    = tid >> 1;        // 0..127
            const int half = tid & 1;         // 0..1
            const int gbase = j * 32 + kt * (KT / 4) + half * 4;
            const int lbase = half * 16;
            for (int q = 0; q < 4; ++q) {
                const float4 v = fcw4[gbase + q];
                fcwt[j][lbase + q * 4 + 0] = v.x;
                fcwt[j][lbase + q * 4 + 1] = v.y;
                fcwt[j][lbase + q * 4 + 2] = v.z;
                fcwt[j][lbase + q * 4 + 3] = v.w;
            }
        }
        __syncthreads();

        // accumulate this k-tile
        for (int kc = 0; kc < KT / 4; ++kc) {
            const float4 rv = sres4[node][kt * (KT / 4) + kc];
            const int k0 = kc * 4;
            o0 = fmaf(rv.x, fcwt[c      ][k0    ], o0);
            o1 = fmaf(rv.x, fcwt[c + 32 ][k0    ], o1);
            o2 = fmaf(rv.x, fcwt[c + 64 ][k0    ], o2);
            o3 = fmaf(rv.x, fcwt[c + 96 ][k0    ], o3);
            o0 = fmaf(rv.y, fcwt[c      ][k0 + 1], o0);
            o1 = fmaf(rv.y, fcwt[c + 32 ][k0 + 1], o1);
            o2 = fmaf(rv.y, fcwt[c + 64 ][k0 + 1], o2);
            o3 = fmaf(rv.y, fcwt[c + 96 ][k0 + 1], o3);
            o0 = fmaf(rv.z, fcwt[c      ][k0 + 2], o0);
            o1 = fmaf(rv.z, fcwt[c + 32 ][k0 + 2], o1);
            o2 = fmaf(rv.z, fcwt[c + 64 ][k0 + 2], o2);
            o3 = fmaf(rv.z, fcwt[c + 96 ][k0 + 2], o3);
            o0 = fmaf(rv.w, fcwt[c      ][k0 + 3], o0);
            o1 = fmaf(rv.w, fcwt[c + 32 ][k0 + 3], o1);
            o2 = fmaf(rv.w, fcwt[c + 64 ][k0 + 3], o2);
            o3 = fmaf(rv.w, fcwt[c + 96 ][k0 + 3], o3);
        }
    }

    // ReLU + store (per instr: 2 nodes x 32 consecutive floats, coalesced)
    {
        const size_t obase = (size_t)(n0 + node) * HIDDEN + c;
        out[obase]      = o0 > 0.0f ? o0 : 0.0f;
        out[obase + 32] = o1 > 0.0f ? o1 : 0.0f;
        out[obase + 64] = o2 > 0.0f ? o2 : 0.0f;
        out[obase + 96] = o3 > 0.0f ? o3 : 0.0f;
    }
}

extern "C" void kernel_launch(void* const* d_in, const int* in_sizes, int n_in,
                              void* d_out, int out_size, void* d_ws, size_t ws_size,
                              hipStream_t stream) {
    const float4* feats4 = (const float4*)d_in[0];  // (N,128) f32
    const int*    paths  = (const int*)d_in[1];     // (8,N,8) int32
    // d_in[2] = init_feats — unused by the reference
    const float4* pw4    = (const float4*)d_in[3];  // (1,8,128) f32
    const float4* fcw4   = (const float4*)d_in[4];  // (128,128) f32
    float* out = (float*)d_out;
    (void)in_sizes; (void)n_in; (void)out_size; (void)d_ws; (void)ws_size;

    PathGCNLayer_61306363183203_kernel<<<N_NODES / NPB, 256, 0, stream>>>(
        feats4, paths, pw4, fcw4, out);
}